// Round 1
// 647.536 us; speedup vs baseline: 1.3854x; 1.3854x over previous
//
#include <hip/hip_runtime.h>

typedef __attribute__((ext_vector_type(8))) __bf16 bf16x8;
typedef __attribute__((ext_vector_type(4))) float f32x4;
typedef __attribute__((ext_vector_type(4))) unsigned int u32x4;
typedef __attribute__((ext_vector_type(2))) unsigned int u32x2;

__device__ __forceinline__ float bf2f(unsigned short u){
    unsigned int x = ((unsigned int)u) << 16;
    return __builtin_bit_cast(float, x);
}
__device__ __forceinline__ unsigned short f2bf(float f){
    unsigned int x = __builtin_bit_cast(unsigned int, f);
    x += 0x7FFFu + ((x >> 16) & 1u);
    return (unsigned short)(x >> 16);
}
__device__ __forceinline__ unsigned int pk2(float a, float b){
    return (unsigned int)f2bf(a) | ((unsigned int)f2bf(b) << 16);
}
__device__ __forceinline__ bf16x8 ldfrag(const unsigned short* p){
    u32x4 v = *reinterpret_cast<const u32x4*>(p);
    return __builtin_bit_cast(bf16x8, v);
}
// fp32 global -> bf16 fragment (8 elements)
__device__ __forceinline__ bf16x8 ldf32(const float* p){
    f32x4 a = *reinterpret_cast<const f32x4*>(p);
    f32x4 b = *reinterpret_cast<const f32x4*>(p + 4);
    u32x4 r;
    r[0] = pk2(a[0], a[1]); r[1] = pk2(a[2], a[3]);
    r[2] = pk2(b[0], b[1]); r[3] = pk2(b[2], b[3]);
    return __builtin_bit_cast(bf16x8, r);
}
__device__ __forceinline__ f32x4 mfma_bf16(bf16x8 a, bf16x8 b, f32x4 c){
    return __builtin_amdgcn_mfma_f32_16x16x32_bf16(a, b, c, 0, 0, 0);
}

#define WINELEMS 1568           // 49*32 per (window,head)
#define NWIN 24576              // 128*3*64

// ---------------- Kernel 1: window-aligned QKV projection ----------------
// One block per (b, wy, wx) window. Gathers the window's 49 pixel rows of x
// (shift folded into the gather), GEMMs against w1 staged in LDS with the
// output-channel permutation g = 3*(32H+eh)+c pre-applied, then writes q/k/v
// window slices fully coalesced (each (H,c) slice is 3136 contiguous bytes).
#define WSTR 104   // LDS fragment row stride in shorts (16B-aligned, conflict-free)
#define OSTR 36    // out_lds pos stride in shorts

__global__ __launch_bounds__(256, 2) void k_qkv(const float* __restrict__ x,
                                                const float* __restrict__ w1,
                                                const float* __restrict__ b1,
                                                unsigned short* __restrict__ qb,
                                                unsigned short* __restrict__ kb,
                                                unsigned short* __restrict__ vb)
{
    __shared__ __align__(16) unsigned short sw1[288 * WSTR];  // 59904 B; reused as out_lds
    __shared__ __align__(16) unsigned short xs[64 * WSTR];    // 13312 B
    __shared__ float bls[288];                                // 1152 B

    const int tid = threadIdx.x;
    const int win = blockIdx.x;
    const int b = win >> 6, wy = (win >> 3) & 7, wx = win & 7;

    // ---- stage x window rows (bf16), rows 49..63 zero ----
    {
        int row = tid >> 2, seg = tid & 3;   // 4 threads/row, 24 floats each
        unsigned int* dstw = reinterpret_cast<unsigned int*>(xs) + row * (WSTR / 2) + seg * 12;
        if (row < 49){
            int iy = row / 7, ix = row - iy * 7;
            int h = wy * 7 + iy + 4; if (h >= 56) h -= 56;   // undo roll(-4)
            int w = wx * 7 + ix + 4; if (w >= 56) w -= 56;
            const float* src = x + ((size_t)b * 3136 + h * 56 + w) * 96 + seg * 24;
#pragma unroll
            for (int jj = 0; jj < 3; ++jj){
                f32x4 v0 = *reinterpret_cast<const f32x4*>(src + jj * 8);
                f32x4 v1 = *reinterpret_cast<const f32x4*>(src + jj * 8 + 4);
                u32x4 p;
                p[0] = pk2(v0[0], v0[1]); p[1] = pk2(v0[2], v0[3]);
                p[2] = pk2(v1[0], v1[1]); p[3] = pk2(v1[2], v1[3]);
                *reinterpret_cast<u32x4*>(dstw + jj * 4) = p;
            }
        } else {
            u32x4 z = {0u, 0u, 0u, 0u};
#pragma unroll
            for (int jj = 0; jj < 3; ++jj) *reinterpret_cast<u32x4*>(dstw + jj * 4) = z;
        }
    }
    // ---- stage w1 (permuted rows: LDS row r' = c*96 + H*32 + eh <- global row 3*(H*32+eh)+c) ----
    for (int i = tid; i < 288 * 12; i += 256){
        int rp = i / 12, seg = i - rp * 12;          // 12 segs x 8 floats = 96 cols
        int c = rp / 96, rem = rp - c * 96;
        const float* src = w1 + (size_t)(3 * rem + c) * 96 + seg * 8;
        f32x4 v0 = *reinterpret_cast<const f32x4*>(src);
        f32x4 v1 = *reinterpret_cast<const f32x4*>(src + 4);
        u32x4 p;
        p[0] = pk2(v0[0], v0[1]); p[1] = pk2(v0[2], v0[3]);
        p[2] = pk2(v1[0], v1[1]); p[3] = pk2(v1[2], v1[3]);
        *reinterpret_cast<u32x4*>(reinterpret_cast<unsigned int*>(sw1) + rp * (WSTR / 2) + seg * 4) = p;
    }
    for (int i = tid; i < 288; i += 256){
        int c = i / 96, rem = i - c * 96;
        bls[i] = b1[3 * rem + c];
    }
    __syncthreads();

    // ---- GEMM: wave w owns rows [w*16, w*16+16) (pos), all 288 cols ----
    const int wave = tid >> 6, lane = tid & 63;
    const int l15 = lane & 15, qd = lane >> 4;

    bf16x8 aX[3];
#pragma unroll
    for (int ks = 0; ks < 3; ++ks)
        aX[ks] = ldfrag(xs + (wave * 16 + l15) * WSTR + ks * 32 + qd * 8);

    f32x4 acc[18];
#pragma unroll
    for (int n = 0; n < 18; ++n){
        f32x4 a = {0.f, 0.f, 0.f, 0.f};
#pragma unroll
        for (int ks = 0; ks < 3; ++ks)
            a = mfma_bf16(aX[ks], ldfrag(sw1 + (n * 16 + l15) * WSTR + ks * 32 + qd * 8), a);
        acc[n] = a;
    }

    float bias[18];
#pragma unroll
    for (int n = 0; n < 18; ++n) bias[n] = bls[n * 16 + l15];

    __syncthreads();   // all waves done reading sw1 -> reuse as out_lds

    // acc -> out_lds in [cH = c*3+H][pos][eh] order (cols are permuted so this is linear)
    unsigned short* out_lds = sw1;
#pragma unroll
    for (int n = 0; n < 18; ++n){
        int cH = n >> 1;
        int eh = ((n & 1) << 4) + l15;
#pragma unroll
        for (int r = 0; r < 4; ++r){
            int pos = wave * 16 + qd * 4 + r;
            out_lds[(cH * 64 + pos) * OSTR + eh] = f2bf(acc[n][r] + bias[n]);
        }
    }
    __syncthreads();

    // ---- coalesced global writes: 9 slices x 49 pos x 32 eh ----
    const size_t wslot = (size_t)(wy * 8 + wx);
    for (int i = tid; i < 9 * 196; i += 256){        // 196 = 49 pos * 4 chunks
        int hc = i / 196, j = i - hc * 196;
        int pos = j >> 2, e8 = j & 3;
        int c = hc / 3, H = hc - c * 3;
        const unsigned int* src = reinterpret_cast<const unsigned int*>(out_lds)
                                + (hc * 64 + pos) * (OSTR / 2) + e8 * 4;
        u32x2 p0 = *reinterpret_cast<const u32x2*>(src);
        u32x2 p1 = *reinterpret_cast<const u32x2*>(src + 2);
        u32x4 v; v[0] = p0[0]; v[1] = p0[1]; v[2] = p1[0]; v[3] = p1[1];
        unsigned short* dstb = (c == 0) ? qb : ((c == 1) ? kb : vb);
        unsigned short* dst = dstb + ((size_t)(b * 3 + H) * 64 + wslot) * WINELEMS
                            + pos * 32 + e8 * 8;
        *reinterpret_cast<u32x4*>(dst) = v;
    }
}

// ---------------- Kernel 2: windowed attention (one wave per (b,H,window)) ----------
__global__ __launch_bounds__(64) void k_attn(const unsigned short* __restrict__ qb,
                                             const unsigned short* __restrict__ kb,
                                             const unsigned short* __restrict__ vb,
                                             unsigned short* __restrict__ ob)
{
    __shared__ unsigned short Vt[32 * 72];   // [eh][key], stride 72
    __shared__ unsigned short P[64 * 72];    // [qrow][key], stride 72
    const int lane = threadIdx.x;
    const int win = blockIdx.x;
    const int wx = win & 7, wy = (win >> 3) & 7;
    const int H = (win >> 6) % 3, b = win / 192;
    const unsigned short* qw = qb + (size_t)win * WINELEMS;
    const unsigned short* kw = kb + (size_t)win * WINELEMS;
    const unsigned short* vw = vb + (size_t)win * WINELEMS;

    // stage V transposed (coalesced read, scatter LDS write)
    for (int i = lane; i < 1568; i += 64){
        int key = i >> 5, eh = i & 31;
        Vt[eh * 72 + key] = vw[i];
    }
    // zero pad keys 49..63
    for (int i = lane; i < 32 * 15; i += 64){
        int eh = i / 15, key = 49 + (i - eh * 15);
        Vt[eh * 72 + key] = 0;
    }

    const int l15 = lane & 15, qd = lane >> 4;

    bf16x8 aQ[4];
#pragma unroll
    for (int tm = 0; tm < 4; ++tm) aQ[tm] = ldfrag(qw + (tm * 16 + l15) * 32 + qd * 8);

    f32x4 S[4][4];
#pragma unroll
    for (int tn = 0; tn < 4; ++tn){
        bf16x8 bK = ldfrag(kw + (tn * 16 + l15) * 32 + qd * 8);
#pragma unroll
        for (int tm = 0; tm < 4; ++tm){
            f32x4 z = {0.f, 0.f, 0.f, 0.f};
            S[tm][tn] = mfma_bf16(aQ[tm], bK, z);
        }
    }

    // masked softmax in C-layout registers; each row lives in one 16-lane group
    const bool rowm = (wy == 7), colm = (wx == 7);
    const float scale = 0.17677669529663687f;   // 1/sqrt(32)
    const float NEGINF = -__builtin_inff();
    float rs[4][4];
#pragma unroll
    for (int tm = 0; tm < 4; ++tm){
#pragma unroll
        for (int r = 0; r < 4; ++r){
            int row = tm * 16 + qd * 4 + r;
            float mx = NEGINF;
#pragma unroll
            for (int tn = 0; tn < 4; ++tn){
                int col = tn * 16 + l15;
                float v = S[tm][tn][r] * scale;
                bool blocked = (col >= 49)
                    || (rowm && ((row >= 28) != (col >= 28)))
                    || (colm && (((row % 7) >= 4) != ((col % 7) >= 4)));
                v = blocked ? NEGINF : v;
                S[tm][tn][r] = v;
                mx = fmaxf(mx, v);
            }
#pragma unroll
            for (int s = 1; s < 16; s <<= 1) mx = fmaxf(mx, __shfl_xor(mx, s, 64));
            float sum = 0.f;
#pragma unroll
            for (int tn = 0; tn < 4; ++tn){
                float e = exp2f((S[tm][tn][r] - mx) * 1.4426950408889634f);
                S[tm][tn][r] = e;
                sum += e;
            }
#pragma unroll
            for (int s = 1; s < 16; s <<= 1) sum += __shfl_xor(sum, s, 64);
            rs[tm][r] = sum;
#pragma unroll
            for (int tn = 0; tn < 4; ++tn)
                P[row * 72 + tn * 16 + l15] = f2bf(S[tm][tn][r]);
        }
    }

    __syncthreads();   // Vt staging + P writes visible

    // O = P * V   (K = 64 keys, 2 k-steps; N = 32 eh, 2 n-tiles)
    f32x4 O[4][2];
#pragma unroll
    for (int tm = 0; tm < 4; ++tm)
#pragma unroll
        for (int tn = 0; tn < 2; ++tn) O[tm][tn] = (f32x4){0.f, 0.f, 0.f, 0.f};

#pragma unroll
    for (int kt = 0; kt < 2; ++kt){
        bf16x8 aP[4];
#pragma unroll
        for (int tm = 0; tm < 4; ++tm)
            aP[tm] = ldfrag((const unsigned short*)P + (tm * 16 + l15) * 72 + kt * 32 + qd * 8);
#pragma unroll
        for (int tn = 0; tn < 2; ++tn){
            bf16x8 bV = ldfrag((const unsigned short*)Vt + (tn * 16 + l15) * 72 + kt * 32 + qd * 8);
#pragma unroll
            for (int tm = 0; tm < 4; ++tm) O[tm][tn] = mfma_bf16(aP[tm], bV, O[tm][tn]);
        }
    }

    // epilogue: normalize, undo window partition + roll(+3), scatter bf16
#pragma unroll
    for (int tm = 0; tm < 4; ++tm){
#pragma unroll
        for (int r = 0; r < 4; ++r){
            int row = tm * 16 + qd * 4 + r;
            if (row < 49){
                float inv = 1.f / rs[tm][r];
                int iy = row / 7, ix = row - iy * 7;
                int h = wy * 7 + iy + 3; if (h >= 56) h -= 56;   // roll +3
                int w = wx * 7 + ix + 3; if (w >= 56) w -= 56;
                size_t base = ((size_t)b * 3136 + h * 56 + w) * 96 + H * 32;
#pragma unroll
                for (int tn = 0; tn < 2; ++tn)
                    ob[base + tn * 16 + l15] = f2bf(O[tm][tn][r] * inv);
            }
        }
    }
}

// ---------------- Kernel 3: output projection -> fp32 out ----------
__global__ __launch_bounds__(256) void k_proj(const unsigned short* __restrict__ ob,
                                              const float* __restrict__ w2,
                                              const float* __restrict__ b2,
                                              float* __restrict__ out)
{
    __shared__ float lds[64 * 100];
    const int tid = threadIdx.x;
    const int wave = tid >> 6, lane = tid & 63;
    const int l15 = lane & 15, qd = lane >> 4;
    const int m0 = blockIdx.x * 64 + wave * 16;

    const unsigned short* xr = ob + (size_t)(m0 + l15) * 96 + qd * 8;
    bf16x8 a0 = ldfrag(xr);
    bf16x8 a1 = ldfrag(xr + 32);
    bf16x8 a2 = ldfrag(xr + 64);

#pragma unroll
    for (int g = 0; g < 6; ++g){
        const float* wr = w2 + (size_t)(g * 16 + l15) * 96 + qd * 8;
        f32x4 a = {0.f, 0.f, 0.f, 0.f};
        a = mfma_bf16(a0, ldf32(wr), a);
        a = mfma_bf16(a1, ldf32(wr + 32), a);
        a = mfma_bf16(a2, ldf32(wr + 64), a);
        float bias = b2[g * 16 + l15];
#pragma unroll
        for (int r = 0; r < 4; ++r)
            lds[(wave * 16 + qd * 4 + r) * 100 + g * 16 + l15] = a[r] + bias;
    }
    __syncthreads();

    // 64 rows x 96 cols fp32 out; thread t: row = t/4, 24-col segment = t%4
    int row = tid >> 2, seg = tid & 3;
    const float* src = lds + row * 100 + seg * 24;
    float* dst = out + ((size_t)blockIdx.x * 64 + row) * 96 + seg * 24;
#pragma unroll
    for (int v = 0; v < 6; ++v){
        f32x4 t4;
#pragma unroll
        for (int j = 0; j < 4; ++j) t4[j] = src[v * 4 + j];
        *reinterpret_cast<f32x4*>(dst + v * 4) = t4;
    }
}

extern "C" void kernel_launch(void* const* d_in, const int* in_sizes, int n_in,
                              void* d_out, int out_size, void* d_ws, size_t ws_size,
                              hipStream_t stream)
{
    const float* x  = (const float*)d_in[0];
    const float* w1 = (const float*)d_in[1];
    const float* b1 = (const float*)d_in[2];
    const float* w2 = (const float*)d_in[3];
    const float* b2 = (const float*)d_in[4];
    float* out = (float*)d_out;

    unsigned short* qb = (unsigned short*)d_ws;
    unsigned short* kb = qb + (size_t)NWIN * WINELEMS;
    unsigned short* vb = kb + (size_t)NWIN * WINELEMS;
    unsigned short* ob = vb + (size_t)NWIN * WINELEMS;

    hipLaunchKernelGGL(k_qkv,  dim3(8192),  dim3(256), 0, stream, x, w1, b1, qb, kb, vb);
    hipLaunchKernelGGL(k_attn, dim3(24576), dim3(64),  0, stream, qb, kb, vb, ob);
    hipLaunchKernelGGL(k_proj, dim3(6272),  dim3(256), 0, stream, ob, w2, b2, out);
}

// Round 2
// 462.648 us; speedup vs baseline: 1.9390x; 1.3996x over previous
//
#include <hip/hip_runtime.h>

typedef __attribute__((ext_vector_type(8))) __bf16 bf16x8;
typedef __attribute__((ext_vector_type(4))) float f32x4;
typedef __attribute__((ext_vector_type(4))) unsigned int u32x4;

__device__ __forceinline__ unsigned short f2bf(float f){
    unsigned int x = __builtin_bit_cast(unsigned int, f);
    x += 0x7FFFu + ((x >> 16) & 1u);
    return (unsigned short)(x >> 16);
}
__device__ __forceinline__ unsigned int pk2(float a, float b){
    return (unsigned int)f2bf(a) | ((unsigned int)f2bf(b) << 16);
}
__device__ __forceinline__ bf16x8 ldfrag(const unsigned short* p){
    u32x4 v = *reinterpret_cast<const u32x4*>(p);
    return __builtin_bit_cast(bf16x8, v);
}
__device__ __forceinline__ f32x4 mfma_bf16(bf16x8 a, bf16x8 b, f32x4 c){
    return __builtin_amdgcn_mfma_f32_16x16x32_bf16(a, b, c, 0, 0, 0);
}

#define XSTR 104        // xs / o_lds row stride (shorts) -> 208 B, 16B-aligned, 2-way banks
#define QKSTR 40        // qk row stride (shorts) -> 80 B, 16B-aligned, 2-way banks
#define VSTR 72         // Vt / P row stride (shorts) -> 144 B, 16B-aligned
#define W1SH 30208      // padded bf16 w1 image: 288*104 + 256 tail (shorts) = 60416 B

// ---------------- Kernel 0: one-time weight prep (fp32 -> bf16, permuted/padded) ------
// w1bf row r' = c*96 + H*32 + eh  <-  w1 row 3*(H*32+eh)+c, stride 104 shorts (zero pad).
// w2bf row-major [96][96].
__global__ __launch_bounds__(256) void k_prep(const float* __restrict__ w1,
                                              const float* __restrict__ w2,
                                              unsigned short* __restrict__ w1bf,
                                              unsigned short* __restrict__ w2bf)
{
    int i = blockIdx.x * 256 + threadIdx.x;
    if (i < 3456){
        int rp = i / 12, seg = i - rp * 12;
        int c = rp / 96, rem = rp - c * 96;
        const float* src = w1 + (size_t)(3 * rem + c) * 96 + seg * 8;
        f32x4 v0 = *reinterpret_cast<const f32x4*>(src);
        f32x4 v1 = *reinterpret_cast<const f32x4*>(src + 4);
        u32x4 p;
        p[0] = pk2(v0[0], v0[1]); p[1] = pk2(v0[2], v0[3]);
        p[2] = pk2(v1[0], v1[1]); p[3] = pk2(v1[2], v1[3]);
        *reinterpret_cast<u32x4*>(w1bf + rp * 104 + seg * 8) = p;
        if (seg == 0){
            u32x4 z = {0u, 0u, 0u, 0u};
            *reinterpret_cast<u32x4*>(w1bf + rp * 104 + 96) = z;
        }
    } else if (i < 3488){
        int j = i - 3456;
        u32x4 z = {0u, 0u, 0u, 0u};
        *reinterpret_cast<u32x4*>(w1bf + 29952 + j * 8) = z;
    } else if (i < 3488 + 1152){
        int j = i - 3488;
        int r = j / 12, seg = j - r * 12;
        const float* src = w2 + (size_t)r * 96 + seg * 8;
        f32x4 v0 = *reinterpret_cast<const f32x4*>(src);
        f32x4 v1 = *reinterpret_cast<const f32x4*>(src + 4);
        u32x4 p;
        p[0] = pk2(v0[0], v0[1]); p[1] = pk2(v0[2], v0[3]);
        p[2] = pk2(v1[0], v1[1]); p[3] = pk2(v1[2], v1[3]);
        *reinterpret_cast<u32x4*>(w2bf + r * 96 + seg * 8) = p;
    }
}

// ---------------- Kernel 1: fully fused QKV + windowed attention + projection --------
// One block per (b, wy, wx) window; 4 waves. No intermediate HBM traffic.
__global__ __launch_bounds__(256, 2) void k_fused(const float* __restrict__ x,
                                                  const unsigned short* __restrict__ w1bf,
                                                  const float* __restrict__ b1,
                                                  const unsigned short* __restrict__ w2bf,
                                                  const float* __restrict__ b2,
                                                  float* __restrict__ out)
{
    __shared__ __align__(16) unsigned short smem[W1SH];      // 60416 B: w1 | qk+Vt+P | o2(fp32)
    __shared__ __align__(16) unsigned short xsm[64 * XSTR];  // 13312 B: x tile | o_lds
    __shared__ float bls[288];

    const int tid = threadIdx.x;
    const int win = blockIdx.x;
    const int b = win >> 6, wy = (win >> 3) & 7, wx = win & 7;
    const int wave = tid >> 6, lane = tid & 63;
    const int l15 = lane & 15, qd = lane >> 4;

    // ---- stage pre-converted w1 (pure 16B copy, no VALU repack) ----
    {
        const u32x4* src = reinterpret_cast<const u32x4*>(w1bf);
        u32x4* dst = reinterpret_cast<u32x4*>(smem);
        for (int i = tid; i < W1SH / 8; i += 256) dst[i] = src[i];
    }
    // ---- stage x window rows (shift folded into gather), rows 49..63 zero ----
    {
        int row = tid >> 2, seg = tid & 3;   // 4 threads/row, 24 floats each
        unsigned int* dstw = reinterpret_cast<unsigned int*>(xsm) + row * (XSTR / 2) + seg * 12;
        if (row < 49){
            int iy = row / 7, ix = row - iy * 7;
            int h = wy * 7 + iy + 4; if (h >= 56) h -= 56;   // undo roll(-4)
            int w = wx * 7 + ix + 4; if (w >= 56) w -= 56;
            const float* src = x + ((size_t)b * 3136 + h * 56 + w) * 96 + seg * 24;
#pragma unroll
            for (int jj = 0; jj < 3; ++jj){
                f32x4 v0 = *reinterpret_cast<const f32x4*>(src + jj * 8);
                f32x4 v1 = *reinterpret_cast<const f32x4*>(src + jj * 8 + 4);
                u32x4 p;
                p[0] = pk2(v0[0], v0[1]); p[1] = pk2(v0[2], v0[3]);
                p[2] = pk2(v1[0], v1[1]); p[3] = pk2(v1[2], v1[3]);
                *reinterpret_cast<u32x4*>(dstw + jj * 4) = p;
            }
        } else {
            u32x4 z = {0u, 0u, 0u, 0u};
#pragma unroll
            for (int jj = 0; jj < 3; ++jj) *reinterpret_cast<u32x4*>(dstw + jj * 4) = z;
        }
    }
    for (int i = tid; i < 288; i += 256){
        int c = i / 96, rem = i - c * 96;
        bls[i] = b1[3 * rem + c];
    }
    __syncthreads();

    // ---- Phase A: QKV GEMM (wave owns 16 rows x all 288 cols) ----
    bf16x8 aX[3];
#pragma unroll
    for (int ks = 0; ks < 3; ++ks)
        aX[ks] = ldfrag(xsm + (wave * 16 + l15) * XSTR + ks * 32 + qd * 8);

    f32x4 acc[18];
#pragma unroll
    for (int n = 0; n < 18; ++n){
        f32x4 a = {0.f, 0.f, 0.f, 0.f};
#pragma unroll
        for (int ks = 0; ks < 3; ++ks)
            a = mfma_bf16(aX[ks], ldfrag(smem + (n * 16 + l15) * XSTR + ks * 32 + qd * 8), a);
        acc[n] = a;
    }
    float bias[18];
#pragma unroll
    for (int n = 0; n < 18; ++n) bias[n] = bls[n * 16 + l15];

    __syncthreads();   // w1 reads done -> alias smem

    // ---- epilogue: q,k -> qk_lds [cH][pos][eh]; v -> Vt [H][eh][key] (transposed) ----
    unsigned short* qk = smem;                         // 6*64*40 = 15360 shorts
    unsigned short* Vt = smem + 6 * 64 * QKSTR;        // 3*32*72 = 6912 shorts
    unsigned short* Pb = Vt + 3 * 32 * VSTR;           // 4 waves * 16*72 = 4608 shorts
#pragma unroll
    for (int n = 0; n < 12; ++n){
        int cH = n >> 1;
        int eh = ((n & 1) << 4) + l15;
#pragma unroll
        for (int r = 0; r < 4; ++r){
            int pos = wave * 16 + qd * 4 + r;
            qk[(cH * 64 + pos) * QKSTR + eh] = f2bf(acc[n][r] + bias[n]);
        }
    }
#pragma unroll
    for (int n = 12; n < 18; ++n){
        int H = (n - 12) >> 1;
        int eh = ((n & 1) << 4) + l15;
#pragma unroll
        for (int r = 0; r < 4; ++r){
            int pos = wave * 16 + qd * 4 + r;
            Vt[(H * 32 + eh) * VSTR + pos] = f2bf(acc[n][r] + bias[n]);
        }
    }
    __syncthreads();

    // ---- Phase B: attention. 12 units = 3 heads x 4 m-tiles; wave handles 3 units ----
    unsigned short* o_lds = xsm;                       // [pos][96ch], stride XSTR
    const bool rowm = (wy == 7), colm = (wx == 7);
    const float scale = 0.17677669529663687f;          // 1/sqrt(32)
    const float NEGINF = -__builtin_inff();
    unsigned short* Pw = Pb + wave * 16 * VSTR;

    for (int u = 0; u < 3; ++u){
        int unit = wave * 3 + u;
        int H = unit >> 2, tm = unit & 3;

        bf16x8 aQ = ldfrag(qk + (H * 64 + tm * 16 + l15) * QKSTR + qd * 8);
        f32x4 S[4];
#pragma unroll
        for (int tn = 0; tn < 4; ++tn){
            bf16x8 bK = ldfrag(qk + ((3 + H) * 64 + tn * 16 + l15) * QKSTR + qd * 8);
            f32x4 z = {0.f, 0.f, 0.f, 0.f};
            S[tn] = mfma_bf16(aQ, bK, z);
        }

        float rs[4];
#pragma unroll
        for (int r = 0; r < 4; ++r){
            int row = tm * 16 + qd * 4 + r;
            float mx = NEGINF;
#pragma unroll
            for (int tn = 0; tn < 4; ++tn){
                int col = tn * 16 + l15;
                float v = S[tn][r] * scale;
                bool blocked = (col >= 49)
                    || (rowm && ((row >= 28) != (col >= 28)))
                    || (colm && (((row % 7) >= 4) != ((col % 7) >= 4)));
                v = blocked ? NEGINF : v;
                S[tn][r] = v;
                mx = fmaxf(mx, v);
            }
#pragma unroll
            for (int s = 1; s < 16; s <<= 1) mx = fmaxf(mx, __shfl_xor(mx, s, 64));
            float sum = 0.f;
#pragma unroll
            for (int tn = 0; tn < 4; ++tn){
                float e = exp2f((S[tn][r] - mx) * 1.4426950408889634f);
                sum += e;
                Pw[(qd * 4 + r) * VSTR + tn * 16 + l15] = f2bf(e);
            }
#pragma unroll
            for (int s = 1; s < 16; s <<= 1) sum += __shfl_xor(sum, s, 64);
            rs[r] = sum;
        }

        // PV: O[16 x 32] = P[16 x 64] * V[64 x 32]
        f32x4 O[2];
        O[0] = (f32x4){0.f, 0.f, 0.f, 0.f};
        O[1] = (f32x4){0.f, 0.f, 0.f, 0.f};
#pragma unroll
        for (int kt = 0; kt < 2; ++kt){
            bf16x8 aP = ldfrag(Pw + l15 * VSTR + kt * 32 + qd * 8);
#pragma unroll
            for (int tn = 0; tn < 2; ++tn){
                bf16x8 bV = ldfrag(Vt + (H * 32 + tn * 16 + l15) * VSTR + kt * 32 + qd * 8);
                O[tn] = mfma_bf16(aP, bV, O[tn]);
            }
        }
#pragma unroll
        for (int r = 0; r < 4; ++r){
            float inv = 1.f / rs[r];
            int pos = tm * 16 + qd * 4 + r;
#pragma unroll
            for (int tn = 0; tn < 2; ++tn)
                o_lds[pos * XSTR + H * 32 + tn * 16 + l15] = f2bf(O[tn][r] * inv);
        }
    }
    __syncthreads();

    // ---- Phase C: output projection (wave owns 16 rows x 96 cols, K=96) ----
    float* o2 = reinterpret_cast<float*>(smem);        // [64][100] fp32, aliases qk/Vt/P
    {
        bf16x8 a0 = ldfrag(o_lds + (wave * 16 + l15) * XSTR + qd * 8);
        bf16x8 a1 = ldfrag(o_lds + (wave * 16 + l15) * XSTR + 32 + qd * 8);
        bf16x8 a2 = ldfrag(o_lds + (wave * 16 + l15) * XSTR + 64 + qd * 8);
#pragma unroll
        for (int n = 0; n < 6; ++n){
            const unsigned short* wr = w2bf + (size_t)(n * 16 + l15) * 96 + qd * 8;
            f32x4 a = {0.f, 0.f, 0.f, 0.f};
            a = mfma_bf16(a0, ldfrag(wr), a);
            a = mfma_bf16(a1, ldfrag(wr + 32), a);
            a = mfma_bf16(a2, ldfrag(wr + 64), a);
            float bias2 = b2[n * 16 + l15];
#pragma unroll
            for (int r = 0; r < 4; ++r)
                o2[(wave * 16 + qd * 4 + r) * 100 + n * 16 + l15] = a[r] + bias2;
        }
    }
    __syncthreads();

    // ---- scatter: 384B-contiguous fp32 rows to rolled (+3) positions ----
    {
        int row = tid >> 2, seg = tid & 3;
        if (row < 49){
            int iy = row / 7, ix = row - iy * 7;
            int h = wy * 7 + iy + 3; if (h >= 56) h -= 56;   // roll +3
            int w = wx * 7 + ix + 3; if (w >= 56) w -= 56;
            const float* src = o2 + row * 100 + seg * 24;
            float* dst = out + ((size_t)b * 3136 + h * 56 + w) * 96 + seg * 24;
#pragma unroll
            for (int v = 0; v < 6; ++v){
                f32x4 t4;
#pragma unroll
                for (int j = 0; j < 4; ++j) t4[j] = src[v * 4 + j];
                *reinterpret_cast<f32x4*>(dst + v * 4) = t4;
            }
        }
    }
}

extern "C" void kernel_launch(void* const* d_in, const int* in_sizes, int n_in,
                              void* d_out, int out_size, void* d_ws, size_t ws_size,
                              hipStream_t stream)
{
    const float* x  = (const float*)d_in[0];
    const float* w1 = (const float*)d_in[1];
    const float* b1 = (const float*)d_in[2];
    const float* w2 = (const float*)d_in[3];
    const float* b2 = (const float*)d_in[4];
    float* out = (float*)d_out;

    unsigned short* w1bf = (unsigned short*)d_ws;
    unsigned short* w2bf = w1bf + W1SH;

    hipLaunchKernelGGL(k_prep,  dim3(19),   dim3(256), 0, stream, w1, w2, w1bf, w2bf);
    hipLaunchKernelGGL(k_fused, dim3(8192), dim3(256), 0, stream, x, w1bf, b1, w2bf, b2, out);
}

// Round 4
// 382.276 us; speedup vs baseline: 2.3467x; 1.2102x over previous
//
#include <hip/hip_runtime.h>

typedef __attribute__((ext_vector_type(8))) __bf16 bf16x8;
typedef __attribute__((ext_vector_type(4))) float f32x4;
typedef __attribute__((ext_vector_type(4))) unsigned int u32x4;

__device__ __forceinline__ unsigned short f2bf(float f){
    unsigned int x = __builtin_bit_cast(unsigned int, f);
    x += 0x7FFFu + ((x >> 16) & 1u);
    return (unsigned short)(x >> 16);
}
__device__ __forceinline__ unsigned int pk2(float a, float b){
    return (unsigned int)f2bf(a) | ((unsigned int)f2bf(b) << 16);
}
__device__ __forceinline__ bf16x8 ldfrag(const unsigned short* p){
    u32x4 v = *reinterpret_cast<const u32x4*>(p);
    return __builtin_bit_cast(bf16x8, v);
}
__device__ __forceinline__ bf16x8 ldf32(const float* p){
    f32x4 a = *reinterpret_cast<const f32x4*>(p);
    f32x4 b = *reinterpret_cast<const f32x4*>(p + 4);
    u32x4 r;
    r[0] = pk2(a[0], a[1]); r[1] = pk2(a[2], a[3]);
    r[2] = pk2(b[0], b[1]); r[3] = pk2(b[2], b[3]);
    return __builtin_bit_cast(bf16x8, r);
}
__device__ __forceinline__ f32x4 mfma_bf16(bf16x8 a, bf16x8 b, f32x4 c){
    return __builtin_amdgcn_mfma_f32_16x16x32_bf16(a, b, c, 0, 0, 0);
}

// workspace layout (shorts): w1f 54*512 = 27648 | w2f 18*512 = 9216 | b1p (float[288])
#define W1F_SH 27648
#define W2F_SH 9216

// ---------------- Kernel 0: one-time weight prep into fragment-major bf16 ----------
// w1f[f = n*3+ks][lane][8]: lane(l15,qd) -> permuted row n*16+l15 (rp = c*96+H*32+eh
// <- orig 3*(H*32+eh)+c), elems ks*32+qd*8.. ; w2f same for w2 (no permutation).
// b1p[rp] = b1 permuted.
__global__ __launch_bounds__(256) void k_prep(const float* __restrict__ w1,
                                              const float* __restrict__ b1,
                                              const float* __restrict__ w2,
                                              unsigned short* __restrict__ w1f,
                                              unsigned short* __restrict__ w2f,
                                              float* __restrict__ b1p)
{
    int i = blockIdx.x * 256 + threadIdx.x;
    if (i < 3456){
        int f = i >> 6, lane = i & 63;
        int n = f / 3, ks = f - n * 3;
        int l15 = lane & 15, qd = lane >> 4;
        int rp = n * 16 + l15;
        int c = rp / 96, rem = rp - c * 96;
        const float* src = w1 + (size_t)(3 * rem + c) * 96 + ks * 32 + qd * 8;
        f32x4 v0 = *reinterpret_cast<const f32x4*>(src);
        f32x4 v1 = *reinterpret_cast<const f32x4*>(src + 4);
        u32x4 p;
        p[0] = pk2(v0[0], v0[1]); p[1] = pk2(v0[2], v0[3]);
        p[2] = pk2(v1[0], v1[1]); p[3] = pk2(v1[2], v1[3]);
        *reinterpret_cast<u32x4*>(w1f + (size_t)f * 512 + lane * 8) = p;
    } else if (i < 4608){
        int j = i - 3456;
        int f = j >> 6, lane = j & 63;
        int n = f / 3, ks = f - n * 3;
        int l15 = lane & 15, qd = lane >> 4;
        const float* src = w2 + (size_t)(n * 16 + l15) * 96 + ks * 32 + qd * 8;
        f32x4 v0 = *reinterpret_cast<const f32x4*>(src);
        f32x4 v1 = *reinterpret_cast<const f32x4*>(src + 4);
        u32x4 p;
        p[0] = pk2(v0[0], v0[1]); p[1] = pk2(v0[2], v0[3]);
        p[2] = pk2(v1[0], v1[1]); p[3] = pk2(v1[2], v1[3]);
        *reinterpret_cast<u32x4*>(w2f + (size_t)f * 512 + lane * 8) = p;
    } else if (i < 4896){
        int rp = i - 4608;
        int c = rp / 96, rem = rp - c * 96;
        b1p[rp] = b1[3 * rem + c];
    }
}

// ---------------- Kernel 1: fused QKV + attention + projection, 38.4 KB LDS ----------
// LDS (shorts): Q [3][64][32] @0 (6144) | K @6144 | Vt [3][32][72] @12288 (6912)
// o_lds aliases Q (phase B output, same swizzled layout); o2 (fp32 [64][100]) aliases K+Vt.
// q/k chunk swizzle: 16B chunk ch stored at ch ^ ((pos>>1)&3)  -> 2-way banks both sides.
__global__ __launch_bounds__(256, 4) void k_fused(const float* __restrict__ x,
                                                  const unsigned short* __restrict__ w1f,
                                                  const float* __restrict__ b1p,
                                                  const unsigned short* __restrict__ w2f,
                                                  const float* __restrict__ b2,
                                                  float* __restrict__ out)
{
    __shared__ __align__(16) unsigned short smem[19200];   // 38400 B
    unsigned short* Qr = smem;
    unsigned short* Kr = smem + 6144;
    unsigned short* Vt = smem + 12288;
    unsigned short* o_lds = smem;                           // aliases Q (safe: see below)
    float* o2 = reinterpret_cast<float*>(smem + 6144);      // aliases K+Vt (phase C only)

    const int tid = threadIdx.x;
    const int win = blockIdx.x;
    const int b = win >> 6, wy = (win >> 3) & 7, wx = win & 7;
    const int wave = tid >> 6, lane = tid & 63;
    const int l15 = lane & 15, qd = lane >> 4;

    // ---- Phase A: QKV GEMM; A-fragments direct from x, B-fragments direct from w1f ----
    {
        int pos = wave * 16 + l15;                   // rows >=49 load garbage (harmless)
        int iy = pos / 7, ix = pos - iy * 7;
        int h = wy * 7 + iy + 4; if (h >= 56) h -= 56;   // undo roll(-4)
        int w = wx * 7 + ix + 4; if (w >= 56) w -= 56;
        const float* xr = x + ((size_t)b * 3136 + h * 56 + w) * 96 + qd * 8;
        bf16x8 aX0 = ldf32(xr);
        bf16x8 aX1 = ldf32(xr + 32);
        bf16x8 aX2 = ldf32(xr + 64);

        f32x4 acc[18];
#pragma unroll
        for (int n = 0; n < 18; ++n){
            const unsigned short* wf = w1f + (size_t)(n * 3) * 512 + lane * 8;
            f32x4 a = {0.f, 0.f, 0.f, 0.f};
            a = mfma_bf16(aX0, ldfrag(wf), a);
            a = mfma_bf16(aX1, ldfrag(wf + 512), a);
            a = mfma_bf16(aX2, ldfrag(wf + 1024), a);
            acc[n] = a;
        }
        float bias[18];
#pragma unroll
        for (int n = 0; n < 18; ++n) bias[n] = b1p[n * 16 + l15];

        // epilogue: q,k -> swizzled packed tiles; v -> Vt transposed
#pragma unroll
        for (int n = 0; n < 18; ++n){
            if (n < 12){
                int c = n / 6, H = (n % 6) >> 1;
                int eh = ((n & 1) << 4) + l15;
                int ch = eh >> 3;
                unsigned short* base = (c == 0 ? Qr : Kr) + H * 2048;
#pragma unroll
                for (int r = 0; r < 4; ++r){
                    int p = wave * 16 + qd * 4 + r;
                    int chs = ch ^ ((p >> 1) & 3);
                    base[p * 32 + chs * 8 + (eh & 7)] = f2bf(acc[n][r] + bias[n]);
                }
            } else {
                int H = (n - 12) >> 1;
                int eh = ((n & 1) << 4) + l15;
#pragma unroll
                for (int r = 0; r < 4; ++r){
                    int p = wave * 16 + qd * 4 + r;
                    Vt[(H * 32 + eh) * 72 + p] = f2bf(acc[n][r] + bias[n]);
                }
            }
        }
    }
    __syncthreads();

    // ---- Phase B: attention, swapped QK^T (S^T = K·Q^T), P kept in registers ----
    const bool rowm = (wy == 7), colm = (wx == 7);
    const float scale = 0.17677669529663687f;        // 1/sqrt(32)
    const float NEGINF = -__builtin_inff();

    // col-side mask bits for the 16 in-thread k positions (k = tn*16 + qd*4 + r)
    unsigned int m49 = 0, m28 = 0, m7 = 0;
#pragma unroll
    for (int tn = 0; tn < 4; ++tn)
#pragma unroll
        for (int r = 0; r < 4; ++r){
            int col = tn * 16 + qd * 4 + r;
            int bit = tn * 4 + r;
            m49 |= (unsigned)(col >= 49) << bit;
            m28 |= (unsigned)(col >= 28) << bit;
            m7  |= (unsigned)((col % 7) >= 4) << bit;
        }
    const int src0 = l15 + 16 * ((2 * qd) & 3);      // P-repack source lanes
    const int src1 = l15 + 16 * ((2 * qd + 1) & 3);
    const int chq = qd ^ ((l15 >> 1) & 3);           // swizzled chunk for q/k frag reads

    for (int u = 0; u < 3; ++u){
        int unit = wave * 3 + u;
        int H = unit >> 2, tm = unit & 3;
        int qrow = tm * 16 + l15;
        bool rhi = (qrow >= 28);
        bool rc7 = ((qrow % 7) >= 4);

        bf16x8 bQ = ldfrag(Qr + H * 2048 + (tm * 16 + l15) * 32 + chq * 8);
        f32x4 S[4];
#pragma unroll
        for (int tn = 0; tn < 4; ++tn){
            bf16x8 aK = ldfrag(Kr + H * 2048 + (tn * 16 + l15) * 32 + chq * 8);
            f32x4 z = {0.f, 0.f, 0.f, 0.f};
            S[tn] = mfma_bf16(aK, bQ, z);            // C: row=k (qd*4+r per tn), col=q (l15)
        }

        float mx = NEGINF;
#pragma unroll
        for (int tn = 0; tn < 4; ++tn)
#pragma unroll
            for (int r = 0; r < 4; ++r){
                int bit = tn * 4 + r;
                float v = S[tn][r] * scale;
                bool blocked = (((m49 >> bit) & 1u) != 0u)
                    || (rowm && (rhi != (((m28 >> bit) & 1u) != 0u)))
                    || (colm && (rc7 != (((m7 >> bit) & 1u) != 0u)));
                v = blocked ? NEGINF : v;
                S[tn][r] = v;
                mx = fmaxf(mx, v);
            }
        mx = fmaxf(mx, __shfl_xor(mx, 16, 64));
        mx = fmaxf(mx, __shfl_xor(mx, 32, 64));
        float sum = 0.f;
#pragma unroll
        for (int tn = 0; tn < 4; ++tn)
#pragma unroll
            for (int r = 0; r < 4; ++r){
                float e = exp2f((S[tn][r] - mx) * 1.4426950408889634f);
                S[tn][r] = e;
                sum += e;
            }
        sum += __shfl_xor(sum, 16, 64);
        sum += __shfl_xor(sum, 32, 64);
        float inv = 1.f / sum;

        // pack P pairs: pkv[tn*2+rp] = bf16x2(S[tn][2rp], S[tn][2rp+1])
        unsigned int pkv[8];
#pragma unroll
        for (int tn = 0; tn < 4; ++tn){
            pkv[tn * 2]     = pk2(S[tn][0], S[tn][1]);
            pkv[tn * 2 + 1] = pk2(S[tn][2], S[tn][3]);
        }

        // PV: O = P·V ; aP word w of kt needs pkv[(2kt+(qd>>1))*2 + (w&1)] from lane src(w>>1)
        f32x4 O[2];
        O[0] = (f32x4){0.f, 0.f, 0.f, 0.f};
        O[1] = (f32x4){0.f, 0.f, 0.f, 0.f};
#pragma unroll
        for (int kt = 0; kt < 2; ++kt){
            u32x4 aw;
#pragma unroll
            for (int w4 = 0; w4 < 4; ++w4){
                int srcl = (w4 < 2) ? src0 : src1;
                unsigned int lo = (unsigned int)__shfl((int)pkv[(2 * kt) * 2 + (w4 & 1)], srcl, 64);
                unsigned int hi = (unsigned int)__shfl((int)pkv[(2 * kt + 1) * 2 + (w4 & 1)], srcl, 64);
                aw[w4] = (qd >= 2) ? hi : lo;
            }
            bf16x8 aP = __builtin_bit_cast(bf16x8, aw);
#pragma unroll
            for (int tn = 0; tn < 2; ++tn){
                bf16x8 bV = ldfrag(Vt + (H * 32 + tn * 16 + l15) * 72 + kt * 32 + qd * 8);
                O[tn] = mfma_bf16(aP, bV, O[tn]);
            }
        }

        // write O into o_lds (aliases Q[H][tm-tile]: only this unit ever touches it)
#pragma unroll
        for (int r = 0; r < 4; ++r){
            float invr = __shfl(inv, qd * 4 + r, 64);
            int p = tm * 16 + qd * 4 + r;
            int swz = (p >> 1) & 3;
#pragma unroll
            for (int tn = 0; tn < 2; ++tn){
                int eh = tn * 16 + l15;
                int chs = (eh >> 3) ^ swz;
                o_lds[(H * 64 + p) * 32 + chs * 8 + (eh & 7)] = f2bf(O[tn][r] * invr);
            }
        }
    }
    __syncthreads();

    // ---- Phase C: output projection (wave owns 16 rows), W2 fragments from global ----
    {
        int prow = wave * 16 + l15;
        bf16x8 a0 = ldfrag(o_lds + (0 * 64 + prow) * 32 + chq * 8);
        bf16x8 a1 = ldfrag(o_lds + (1 * 64 + prow) * 32 + chq * 8);
        bf16x8 a2 = ldfrag(o_lds + (2 * 64 + prow) * 32 + chq * 8);
#pragma unroll
        for (int n = 0; n < 6; ++n){
            const unsigned short* wf = w2f + (size_t)(n * 3) * 512 + lane * 8;
            f32x4 a = {0.f, 0.f, 0.f, 0.f};
            a = mfma_bf16(a0, ldfrag(wf), a);
            a = mfma_bf16(a1, ldfrag(wf + 512), a);
            a = mfma_bf16(a2, ldfrag(wf + 1024), a);
            float bias2 = b2[n * 16 + l15];
#pragma unroll
            for (int r = 0; r < 4; ++r)
                o2[(wave * 16 + qd * 4 + r) * 100 + n * 16 + l15] = a[r] + bias2;
        }
    }
    __syncthreads();

    // ---- scatter: 384B-contiguous fp32 rows to rolled (+3) positions ----
    {
        int row = tid >> 2, seg = tid & 3;
        if (row < 49){
            int iy = row / 7, ix = row - iy * 7;
            int h = wy * 7 + iy + 3; if (h >= 56) h -= 56;
            int w = wx * 7 + ix + 3; if (w >= 56) w -= 56;
            const float* src = o2 + row * 100 + seg * 24;
            float* dst = out + ((size_t)b * 3136 + h * 56 + w) * 96 + seg * 24;
#pragma unroll
            for (int v = 0; v < 6; ++v){
                f32x4 t4;
#pragma unroll
                for (int j = 0; j < 4; ++j) t4[j] = src[v * 4 + j];
                *reinterpret_cast<f32x4*>(dst + v * 4) = t4;
            }
        }
    }
}

extern "C" void kernel_launch(void* const* d_in, const int* in_sizes, int n_in,
                              void* d_out, int out_size, void* d_ws, size_t ws_size,
                              hipStream_t stream)
{
    const float* x  = (const float*)d_in[0];
    const float* w1 = (const float*)d_in[1];
    const float* b1 = (const float*)d_in[2];
    const float* w2 = (const float*)d_in[3];
    const float* b2 = (const float*)d_in[4];
    float* out = (float*)d_out;

    unsigned short* w1f = (unsigned short*)d_ws;
    unsigned short* w2f = w1f + W1F_SH;
    float* b1p = (float*)(w2f + W2F_SH);

    hipLaunchKernelGGL(k_prep,  dim3(20),   dim3(256), 0, stream, w1, b1, w2, w1f, w2f, b1p);
    hipLaunchKernelGGL(k_fused, dim3(8192), dim3(256), 0, stream, x, w1f, b1p, w2f, b2, out);
}